// Round 5
// baseline (580.542 us; speedup 1.0000x reference)
//
#include <hip/hip_runtime.h>
#include <cstddef>

// Problem constants (reference: B=32, L=128, N=64, D=64, H=4, DH=16)
#define BB   32
#define LL   128
#define NN   64
#define DD   64
#define HH   4

typedef float v2f __attribute__((ext_vector_type(2)));

__device__ __forceinline__ float bcast(float v, int l) {
    return __int_as_float(__builtin_amdgcn_readlane(__float_as_int(v), l));
}
__device__ __forceinline__ float sigmoidf_(float x) {
    return 1.0f / (1.0f + __expf(-x));
}
__device__ __forceinline__ float tanhf_(float x) {
    float e = __expf(2.0f * x);
    return 1.0f - 2.0f / (e + 1.0f);
}

// Load the 4 gate rows (i,f,g,o) of hidden unit u for variable n into
// packed register pairs: wif[k] = {Wi[k], Wf[k]}, wgo[k] = {Wg[k], Wo[k]}.
// Incremental repack keeps transient VGPR pressure ~ +8.
__device__ __forceinline__ void load_gate_rows(const float* __restrict__ W,
                                               int n, int u,
                                               v2f (&wif)[64], v2f (&wgo)[64]) {
    const float4* Ri = reinterpret_cast<const float4*>(W + ((size_t)n * 256 + u      ) * 64);
    const float4* Rf = reinterpret_cast<const float4*>(W + ((size_t)n * 256 + u +  64) * 64);
    const float4* Rg = reinterpret_cast<const float4*>(W + ((size_t)n * 256 + u + 128) * 64);
    const float4* Ro = reinterpret_cast<const float4*>(W + ((size_t)n * 256 + u + 192) * 64);
#pragma unroll
    for (int q = 0; q < 16; ++q) {
        float4 a = Ri[q], b = Rf[q];
        wif[4 * q + 0] = v2f{a.x, b.x};
        wif[4 * q + 1] = v2f{a.y, b.y};
        wif[4 * q + 2] = v2f{a.z, b.z};
        wif[4 * q + 3] = v2f{a.w, b.w};
        float4 c = Rg[q], d = Ro[q];
        wgo[4 * q + 0] = v2f{c.x, d.x};
        wgo[4 * q + 1] = v2f{c.y, d.y};
        wgo[4 * q + 2] = v2f{c.z, d.z};
        wgo[4 * q + 3] = v2f{c.w, d.w};
    }
}

// ---------------------------------------------------------------------------
// Encoder: one wave per (variable n, batch b). Lane u owns hidden unit u and
// all 4 gate rows. No LDS, no barriers; h broadcast via v_readlane.
// Online-softmax temporal attention pooling fused.
// ---------------------------------------------------------------------------
__global__ __launch_bounds__(64)
void enc_kernel(const float* __restrict__ X,
                const float* __restrict__ Wih,
                const float* __restrict__ Whh,
                const float* __restrict__ bias,
                const float* __restrict__ poolw,
                const float* __restrict__ poolb,
                float* __restrict__ Cws)   // [B][N][D]
{
    const int n = blockIdx.x >> 5;
    const int b = blockIdx.x & 31;
    const int u = threadIdx.x;

    v2f wif[64], wgo[64];
    load_gate_rows(Whh, n, u, wif, wgo);

    const float* Bn = bias + n * 256;
    const v2f bif = {Bn[u],       Bn[u +  64]};
    const v2f bgo = {Bn[u + 128], Bn[u + 192]};
    const float* Wn = Wih + n * 256;           // [4D][1]
    const v2f xif = {Wn[u],       Wn[u +  64]};
    const v2f xgo = {Wn[u + 128], Wn[u + 192]};
    const float pwu = poolw[n * DD + u];
    const float pbn = poolb[n];

    // x series for this (n,b): t = u and t = u+64 (both indices in-bounds)
    const float x0 = X[(size_t)b * (LL * NN) + (size_t)u * NN + n];
    const float x1 = X[(size_t)b * (LL * NN) + (size_t)(u + 64) * NN + n];

    float h = 0.0f, c = 0.0f;
    float m = -1e30f, s = 0.0f, pa = 0.0f;

#pragma unroll 1
    for (int t = 0; t < LL - 1; ++t) {
        const float xt = bcast((t < 64) ? x0 : x1, t & 63);
        v2f aif = __builtin_elementwise_fma(xif, v2f{xt, xt}, bif);
        v2f ago = __builtin_elementwise_fma(xgo, v2f{xt, xt}, bgo);
#pragma unroll
        for (int k = 0; k < 64; ++k) {
            const float hk = bcast(h, k);
            const v2f hh = {hk, hk};
            aif = __builtin_elementwise_fma(wif[k], hh, aif);
            ago = __builtin_elementwise_fma(wgo[k], hh, ago);
        }
        const float gi = sigmoidf_(aif.x), gf = sigmoidf_(aif.y);
        const float gg = tanhf_(ago.x),   go = sigmoidf_(ago.y);
        c = gf * c + gi * gg;
        h = go * tanhf_(c);

        // pooling score: full-wave reduce of h*pw
        float p = h * pwu;
#pragma unroll
        for (int off = 32; off >= 1; off >>= 1) p += __shfl_xor(p, off, 64);
        const float score = p + pbn;

        // online softmax (uniform across wave)
        const float mn   = fmaxf(m, score);
        const float corr = __expf(m - mn);
        const float wgt  = __expf(score - mn);
        s  = s * corr + wgt;
        pa = pa * corr + wgt * h;   // per-lane weighted accumulation of h[u]
        m  = mn;
    }

    Cws[(size_t)b * (NN * DD) + (size_t)n * DD + u] = pa / s;
}

// ---------------------------------------------------------------------------
// Attention per (b, h): qkv slice -> scores -> softmax -> o head slice.
// (unchanged from R4 — correct and tiny)
// ---------------------------------------------------------------------------
__global__ __launch_bounds__(256)
void attn_kernel(const float* __restrict__ Cws,
                 const float* __restrict__ Wqkv,
                 const float* __restrict__ bqkv,
                 float* __restrict__ Ows)
{
    const int b = blockIdx.x >> 2;
    const int h = blockIdx.x & 3;
    const int tid = threadIdx.x;

    __shared__ float Cl[64][65];
    __shared__ float Wl[48][65];
    __shared__ float biasl[48];
    __shared__ float ql[64][17], kl[64][17], vl[64][17];
    __shared__ float sl[64][65];

    for (int i = tid; i < 64 * 64; i += 256)
        Cl[i >> 6][i & 63] = Cws[(size_t)b * (NN * DD) + i];
    for (int i = tid; i < 48 * 64; i += 256) {
        int row = i >> 6, col = i & 63;
        int grp = row >> 4, r = row & 15;
        Wl[row][col] = Wqkv[(size_t)(grp * 64 + h * 16 + r) * DD + col];
    }
    if (tid < 48) {
        int grp = tid >> 4, r = tid & 15;
        biasl[tid] = bqkv[grp * 64 + h * 16 + r];
    }
    __syncthreads();

    for (int i = tid; i < 3 * 64 * 16; i += 256) {
        int sec = i >> 10;
        int rem = i & 1023;
        int nn = rem >> 4, dh = rem & 15;
        float acc = biasl[sec * 16 + dh];
        const float* wr = &Wl[sec * 16 + dh][0];
#pragma unroll 16
        for (int k = 0; k < 64; ++k) acc = fmaf(Cl[nn][k], wr[k], acc);
        if      (sec == 0) ql[nn][dh] = acc;
        else if (sec == 1) kl[nn][dh] = acc;
        else               vl[nn][dh] = acc;
    }
    __syncthreads();

    for (int i = tid; i < 64 * 64; i += 256) {
        int nn = i >> 6, mm = i & 63;
        float acc = 0.0f;
#pragma unroll
        for (int d = 0; d < 16; ++d) acc = fmaf(ql[nn][d], kl[mm][d], acc);
        sl[nn][mm] = acc * 0.25f;
    }
    __syncthreads();

    if (tid < 64) {
        float mx = -1e30f;
        for (int mm = 0; mm < 64; ++mm) mx = fmaxf(mx, sl[tid][mm]);
        float ss = 0.0f;
        for (int mm = 0; mm < 64; ++mm) {
            float e = __expf(sl[tid][mm] - mx);
            sl[tid][mm] = e;
            ss += e;
        }
        float inv = 1.0f / ss;
        for (int mm = 0; mm < 64; ++mm) sl[tid][mm] *= inv;
    }
    __syncthreads();

    for (int i = tid; i < 64 * 16; i += 256) {
        int nn = i >> 4, dh = i & 15;
        float acc = 0.0f;
#pragma unroll 16
        for (int mm = 0; mm < 64; ++mm) acc = fmaf(sl[nn][mm], vl[mm][dh], acc);
        Ows[(size_t)b * (NN * DD) + (size_t)nn * DD + h * 16 + dh] = acc;
    }
}

__global__ __launch_bounds__(256)
void proj_kernel(const float* __restrict__ Ows,
                 const float* __restrict__ Wo,
                 const float* __restrict__ bo,
                 float* __restrict__ Cstar)
{
    const int b = blockIdx.x;
    const int tid = threadIdx.x;
    __shared__ float Ol[64][65];
    __shared__ float Wl[64][65];

    for (int i = tid; i < 64 * 64; i += 256) {
        Ol[i >> 6][i & 63] = Ows[(size_t)b * (NN * DD) + i];
        Wl[i >> 6][i & 63] = Wo[i];
    }
    __syncthreads();

    for (int i = tid; i < 64 * 64; i += 256) {
        int nn = i >> 6, d = i & 63;
        float acc = bo[d];
#pragma unroll 16
        for (int k = 0; k < 64; ++k) acc = fmaf(Ol[nn][k], Wl[d][k], acc);
        Cstar[(size_t)b * (NN * DD) + i] = acc;
    }
}

// ---------------------------------------------------------------------------
// Decoder init: h0/c0 = tanh(Cs @ W^T + b) per (n, b). One wave per (n,b),
// lane u computes unit u. Output [n][b][u].
// ---------------------------------------------------------------------------
__global__ __launch_bounds__(64)
void dec_init_kernel(const float* __restrict__ Cstar,
                     const float* __restrict__ WhI,
                     const float* __restrict__ bhI,
                     const float* __restrict__ WcI,
                     const float* __restrict__ bcI,
                     float* __restrict__ H0,
                     float* __restrict__ C0)
{
    const int n = blockIdx.x >> 5;
    const int b = blockIdx.x & 31;
    const int u = threadIdx.x;

    const float cs = Cstar[(size_t)b * (NN * DD) + (size_t)n * DD + u];
    const float4* Rh = reinterpret_cast<const float4*>(WhI + ((size_t)n * DD + u) * DD);
    const float4* Rc = reinterpret_cast<const float4*>(WcI + ((size_t)n * DD + u) * DD);
    float ah = bhI[n * DD + u];
    float ac = bcI[n * DD + u];
#pragma unroll
    for (int q = 0; q < 16; ++q) {
        const float4 wh = Rh[q], wc = Rc[q];
        float k0 = bcast(cs, 4 * q + 0);
        float k1 = bcast(cs, 4 * q + 1);
        float k2 = bcast(cs, 4 * q + 2);
        float k3 = bcast(cs, 4 * q + 3);
        ah = fmaf(wh.x, k0, ah); ah = fmaf(wh.y, k1, ah);
        ah = fmaf(wh.z, k2, ah); ah = fmaf(wh.w, k3, ah);
        ac = fmaf(wc.x, k0, ac); ac = fmaf(wc.y, k1, ac);
        ac = fmaf(wc.z, k2, ac); ac = fmaf(wc.w, k3, ac);
    }
    const size_t idx = ((size_t)n * BB + b) * DD + u;
    H0[idx] = tanhf_(ah);
    C0[idx] = tanhf_(ac);
}

// ---------------------------------------------------------------------------
// Decoder: one wave per (n, b); zero inputs; per-step y = h.ow + ob.
// ---------------------------------------------------------------------------
__global__ __launch_bounds__(64)
void dec_kernel(const float* __restrict__ Whh,
                const float* __restrict__ bias,
                const float* __restrict__ ow,
                const float* __restrict__ ob,
                const float* __restrict__ H0,
                const float* __restrict__ C0,
                float* __restrict__ recon,        // [B][L-1][N]
                float* __restrict__ pred)         // [B][N]
{
    const int n = blockIdx.x >> 5;
    const int b = blockIdx.x & 31;
    const int u = threadIdx.x;

    v2f wif[64], wgo[64];
    load_gate_rows(Whh, n, u, wif, wgo);

    const float* Bn = bias + n * 256;
    const v2f bif = {Bn[u],       Bn[u +  64]};
    const v2f bgo = {Bn[u + 128], Bn[u + 192]};
    const float owu = ow[n * DD + u];
    const float obn = ob[n];

    const size_t idx = ((size_t)n * BB + b) * DD + u;
    float h = H0[idx];
    float c = C0[idx];

#pragma unroll 1
    for (int t = 0; t < LL; ++t) {
        v2f aif = bif, ago = bgo;
#pragma unroll
        for (int k = 0; k < 64; ++k) {
            const float hk = bcast(h, k);
            const v2f hh = {hk, hk};
            aif = __builtin_elementwise_fma(wif[k], hh, aif);
            ago = __builtin_elementwise_fma(wgo[k], hh, ago);
        }
        const float gi = sigmoidf_(aif.x), gf = sigmoidf_(aif.y);
        const float gg = tanhf_(ago.x),   go = sigmoidf_(ago.y);
        c = gf * c + gi * gg;
        h = go * tanhf_(c);

        float p = h * owu;
#pragma unroll
        for (int off = 32; off >= 1; off >>= 1) p += __shfl_xor(p, off, 64);
        if (u == 0) {
            const float y = p + obn;
            if (t < LL - 1)
                recon[(size_t)b * ((LL - 1) * NN) + (size_t)t * NN + n] = y;
            else
                pred[(size_t)b * NN + n] = y;
        }
    }
}

extern "C" void kernel_launch(void* const* d_in, const int* in_sizes, int n_in,
                              void* d_out, int out_size, void* d_ws, size_t ws_size,
                              hipStream_t stream) {
    (void)in_sizes; (void)n_in; (void)out_size; (void)ws_size;

    const float* X         = (const float*)d_in[0];
    const float* enc_Wih   = (const float*)d_in[1];
    const float* enc_Whh   = (const float*)d_in[2];
    const float* enc_b     = (const float*)d_in[3];
    const float* pool_w    = (const float*)d_in[4];
    const float* pool_b    = (const float*)d_in[5];
    const float* attn_Wqkv = (const float*)d_in[6];
    const float* attn_bqkv = (const float*)d_in[7];
    const float* attn_Wo   = (const float*)d_in[8];
    const float* attn_bo   = (const float*)d_in[9];
    // d_in[10] = dec_Wih: multiplied by all-zero inputs -> unused
    const float* dec_Whh   = (const float*)d_in[11];
    const float* dec_b     = (const float*)d_in[12];
    const float* init_h_W  = (const float*)d_in[13];
    const float* init_h_b  = (const float*)d_in[14];
    const float* init_c_W  = (const float*)d_in[15];
    const float* init_c_b  = (const float*)d_in[16];
    const float* out_w     = (const float*)d_in[17];
    const float* out_b     = (const float*)d_in[18];

    float* out   = (float*)d_out;
    float* recon = out;                                     // B*(L-1)*N
    float* pred  = out + (size_t)BB * (LL - 1) * NN;        // B*N
    float* cstar = pred + (size_t)BB * NN;                  // B*N*D

    float* Cws = (float*)d_ws;                              // [B][N][D]
    float* Ows = Cws + (size_t)BB * NN * DD;                // [B][N][D]
    // After proj, Cws/Ows are dead -> reuse for H0/C0 ([N][B][D] each)
    float* H0 = Cws;
    float* C0 = Ows;

    enc_kernel<<<dim3(NN * BB), dim3(64), 0, stream>>>(
        X, enc_Wih, enc_Whh, enc_b, pool_w, pool_b, Cws);

    attn_kernel<<<dim3(BB * HH), dim3(256), 0, stream>>>(
        Cws, attn_Wqkv, attn_bqkv, Ows);

    proj_kernel<<<dim3(BB), dim3(256), 0, stream>>>(
        Ows, attn_Wo, attn_bo, cstar);

    dec_init_kernel<<<dim3(NN * BB), dim3(64), 0, stream>>>(
        cstar, init_h_W, init_h_b, init_c_W, init_c_b, H0, C0);

    dec_kernel<<<dim3(NN * BB), dim3(64), 0, stream>>>(
        dec_Whh, dec_b, out_w, out_b, H0, C0, recon, pred);
}

// Round 6
// 578.447 us; speedup vs baseline: 1.0036x; 1.0036x over previous
//
#include <hip/hip_runtime.h>
#include <cstddef>

// Problem constants (reference: B=32, L=128, N=64, D=64, H=4, DH=16)
#define BB   32
#define LL   128
#define NN   64
#define DD   64
#define HH   4

typedef float v2f __attribute__((ext_vector_type(2)));

__device__ __forceinline__ float bcast(float v, int l) {
    return __int_as_float(__builtin_amdgcn_readlane(__float_as_int(v), l));
}
__device__ __forceinline__ float sigmoidf_(float x) {
    return 1.0f / (1.0f + __expf(-x));
}
__device__ __forceinline__ float tanhf_(float x) {
    float e = __expf(2.0f * x);
    return 1.0f - 2.0f / (e + 1.0f);
}

// Load the 4 gate rows (i,f,g,o) of hidden unit u for variable n into
// packed register pairs: wif[k] = {Wi[k], Wf[k]}, wgo[k] = {Wg[k], Wo[k]}.
__device__ __forceinline__ void load_gate_rows(const float* __restrict__ W,
                                               int n, int u,
                                               v2f (&wif)[64], v2f (&wgo)[64]) {
    const float4* Ri = reinterpret_cast<const float4*>(W + ((size_t)n * 256 + u      ) * 64);
    const float4* Rf = reinterpret_cast<const float4*>(W + ((size_t)n * 256 + u +  64) * 64);
    const float4* Rg = reinterpret_cast<const float4*>(W + ((size_t)n * 256 + u + 128) * 64);
    const float4* Ro = reinterpret_cast<const float4*>(W + ((size_t)n * 256 + u + 192) * 64);
#pragma unroll
    for (int q = 0; q < 16; ++q) {
        float4 a = Ri[q], b = Rf[q];
        wif[4 * q + 0] = v2f{a.x, b.x};
        wif[4 * q + 1] = v2f{a.y, b.y};
        wif[4 * q + 2] = v2f{a.z, b.z};
        wif[4 * q + 3] = v2f{a.w, b.w};
        float4 c = Rg[q], d = Ro[q];
        wgo[4 * q + 0] = v2f{c.x, d.x};
        wgo[4 * q + 1] = v2f{c.y, d.y};
        wgo[4 * q + 2] = v2f{c.z, d.z};
        wgo[4 * q + 3] = v2f{c.w, d.w};
    }
}

// ---------------------------------------------------------------------------
// Encoder: one wave per (variable n, batch b). Lane u owns hidden unit u and
// all 4 gate rows (256 VGPRs of weights — hence launch_bounds(64,1) to give
// the allocator the full 512-reg budget; do NOT let it rematerialize loads).
// No LDS, no barriers; h broadcast via v_readlane. Online-softmax pooling.
// ---------------------------------------------------------------------------
__global__ __launch_bounds__(64, 1)
void enc_kernel(const float* __restrict__ X,
                const float* __restrict__ Wih,
                const float* __restrict__ Whh,
                const float* __restrict__ bias,
                const float* __restrict__ poolw,
                const float* __restrict__ poolb,
                float* __restrict__ Cws)   // [B][N][D]
{
    const int n = blockIdx.x >> 5;
    const int b = blockIdx.x & 31;
    const int u = threadIdx.x;

    v2f wif[64], wgo[64];
    load_gate_rows(Whh, n, u, wif, wgo);

    const float* Bn = bias + n * 256;
    const v2f bif = {Bn[u],       Bn[u +  64]};
    const v2f bgo = {Bn[u + 128], Bn[u + 192]};
    const float* Wn = Wih + n * 256;           // [4D][1]
    const v2f xif = {Wn[u],       Wn[u +  64]};
    const v2f xgo = {Wn[u + 128], Wn[u + 192]};
    const float pwu = poolw[n * DD + u];
    const float pbn = poolb[n];

    // x series for this (n,b): lane u holds t=u and t=u+64
    const float x0 = X[(size_t)b * (LL * NN) + (size_t)u * NN + n];
    const float x1 = X[(size_t)b * (LL * NN) + (size_t)(u + 64) * NN + n];

    float h = 0.0f, c = 0.0f;
    float m = -1e30f, s = 0.0f, pa = 0.0f;

#pragma unroll 1
    for (int t = 0; t < LL - 1; ++t) {
        const float xt = bcast((t < 64) ? x0 : x1, t & 63);
        v2f aif = __builtin_elementwise_fma(xif, v2f{xt, xt}, bif);
        v2f ago = __builtin_elementwise_fma(xgo, v2f{xt, xt}, bgo);
#pragma unroll
        for (int k = 0; k < 64; ++k) {
            const float hk = bcast(h, k);
            const v2f hh = {hk, hk};
            aif = __builtin_elementwise_fma(wif[k], hh, aif);
            ago = __builtin_elementwise_fma(wgo[k], hh, ago);
        }
        const float gi = sigmoidf_(aif.x), gf = sigmoidf_(aif.y);
        const float gg = tanhf_(ago.x),   go = sigmoidf_(ago.y);
        c = gf * c + gi * gg;
        h = go * tanhf_(c);

        // pooling score: full-wave reduce of h*pw
        float p = h * pwu;
#pragma unroll
        for (int off = 32; off >= 1; off >>= 1) p += __shfl_xor(p, off, 64);
        const float score = p + pbn;

        // online softmax (uniform across wave)
        const float mn   = fmaxf(m, score);
        const float corr = __expf(m - mn);
        const float wgt  = __expf(score - mn);
        s  = s * corr + wgt;
        pa = pa * corr + wgt * h;
        m  = mn;
    }

    Cws[(size_t)b * (NN * DD) + (size_t)n * DD + u] = pa / s;
}

// ---------------------------------------------------------------------------
// Attention per (b, h): qkv slice -> scores -> softmax -> o head slice.
// ---------------------------------------------------------------------------
__global__ __launch_bounds__(256)
void attn_kernel(const float* __restrict__ Cws,
                 const float* __restrict__ Wqkv,
                 const float* __restrict__ bqkv,
                 float* __restrict__ Ows)
{
    const int b = blockIdx.x >> 2;
    const int h = blockIdx.x & 3;
    const int tid = threadIdx.x;

    __shared__ float Cl[64][65];
    __shared__ float Wl[48][65];
    __shared__ float biasl[48];
    __shared__ float ql[64][17], kl[64][17], vl[64][17];
    __shared__ float sl[64][65];

    for (int i = tid; i < 64 * 64; i += 256)
        Cl[i >> 6][i & 63] = Cws[(size_t)b * (NN * DD) + i];
    for (int i = tid; i < 48 * 64; i += 256) {
        int row = i >> 6, col = i & 63;
        int grp = row >> 4, r = row & 15;
        Wl[row][col] = Wqkv[(size_t)(grp * 64 + h * 16 + r) * DD + col];
    }
    if (tid < 48) {
        int grp = tid >> 4, r = tid & 15;
        biasl[tid] = bqkv[grp * 64 + h * 16 + r];
    }
    __syncthreads();

    for (int i = tid; i < 3 * 64 * 16; i += 256) {
        int sec = i >> 10;
        int rem = i & 1023;
        int nn = rem >> 4, dh = rem & 15;
        float acc = biasl[sec * 16 + dh];
        const float* wr = &Wl[sec * 16 + dh][0];
#pragma unroll 16
        for (int k = 0; k < 64; ++k) acc = fmaf(Cl[nn][k], wr[k], acc);
        if      (sec == 0) ql[nn][dh] = acc;
        else if (sec == 1) kl[nn][dh] = acc;
        else               vl[nn][dh] = acc;
    }
    __syncthreads();

    for (int i = tid; i < 64 * 64; i += 256) {
        int nn = i >> 6, mm = i & 63;
        float acc = 0.0f;
#pragma unroll
        for (int d = 0; d < 16; ++d) acc = fmaf(ql[nn][d], kl[mm][d], acc);
        sl[nn][mm] = acc * 0.25f;
    }
    __syncthreads();

    if (tid < 64) {
        float mx = -1e30f;
        for (int mm = 0; mm < 64; ++mm) mx = fmaxf(mx, sl[tid][mm]);
        float ss = 0.0f;
        for (int mm = 0; mm < 64; ++mm) {
            float e = __expf(sl[tid][mm] - mx);
            sl[tid][mm] = e;
            ss += e;
        }
        float inv = 1.0f / ss;
        for (int mm = 0; mm < 64; ++mm) sl[tid][mm] *= inv;
    }
    __syncthreads();

    for (int i = tid; i < 64 * 16; i += 256) {
        int nn = i >> 4, dh = i & 15;
        float acc = 0.0f;
#pragma unroll 16
        for (int mm = 0; mm < 64; ++mm) acc = fmaf(sl[nn][mm], vl[mm][dh], acc);
        Ows[(size_t)b * (NN * DD) + (size_t)nn * DD + h * 16 + dh] = acc;
    }
}

__global__ __launch_bounds__(256)
void proj_kernel(const float* __restrict__ Ows,
                 const float* __restrict__ Wo,
                 const float* __restrict__ bo,
                 float* __restrict__ Cstar)
{
    const int b = blockIdx.x;
    const int tid = threadIdx.x;
    __shared__ float Ol[64][65];
    __shared__ float Wl[64][65];

    for (int i = tid; i < 64 * 64; i += 256) {
        Ol[i >> 6][i & 63] = Ows[(size_t)b * (NN * DD) + i];
        Wl[i >> 6][i & 63] = Wo[i];
    }
    __syncthreads();

    for (int i = tid; i < 64 * 64; i += 256) {
        int nn = i >> 6, d = i & 63;
        float acc = bo[d];
#pragma unroll 16
        for (int k = 0; k < 64; ++k) acc = fmaf(Ol[nn][k], Wl[d][k], acc);
        Cstar[(size_t)b * (NN * DD) + i] = acc;
    }
}

// ---------------------------------------------------------------------------
// Decoder init: h0/c0 = tanh(Cs @ W^T + b) per (n, b). One wave per (n,b).
// Kept separate from dec_kernel so its transient weight rows don't add to
// dec_kernel's VGPR peak.
// ---------------------------------------------------------------------------
__global__ __launch_bounds__(64)
void dec_init_kernel(const float* __restrict__ Cstar,
                     const float* __restrict__ WhI,
                     const float* __restrict__ bhI,
                     const float* __restrict__ WcI,
                     const float* __restrict__ bcI,
                     float* __restrict__ H0,
                     float* __restrict__ C0)
{
    const int n = blockIdx.x >> 5;
    const int b = blockIdx.x & 31;
    const int u = threadIdx.x;

    const float cs = Cstar[(size_t)b * (NN * DD) + (size_t)n * DD + u];
    const float4* Rh = reinterpret_cast<const float4*>(WhI + ((size_t)n * DD + u) * DD);
    const float4* Rc = reinterpret_cast<const float4*>(WcI + ((size_t)n * DD + u) * DD);
    float ah = bhI[n * DD + u];
    float ac = bcI[n * DD + u];
#pragma unroll
    for (int q = 0; q < 16; ++q) {
        const float4 wh = Rh[q], wc = Rc[q];
        float k0 = bcast(cs, 4 * q + 0);
        float k1 = bcast(cs, 4 * q + 1);
        float k2 = bcast(cs, 4 * q + 2);
        float k3 = bcast(cs, 4 * q + 3);
        ah = fmaf(wh.x, k0, ah); ah = fmaf(wh.y, k1, ah);
        ah = fmaf(wh.z, k2, ah); ah = fmaf(wh.w, k3, ah);
        ac = fmaf(wc.x, k0, ac); ac = fmaf(wc.y, k1, ac);
        ac = fmaf(wc.z, k2, ac); ac = fmaf(wc.w, k3, ac);
    }
    const size_t idx = ((size_t)n * BB + b) * DD + u;
    H0[idx] = tanhf_(ah);
    C0[idx] = tanhf_(ac);
}

// ---------------------------------------------------------------------------
// Decoder: one wave per (n, b); zero inputs; per-step y = h.ow + ob.
// ---------------------------------------------------------------------------
__global__ __launch_bounds__(64, 1)
void dec_kernel(const float* __restrict__ Whh,
                const float* __restrict__ bias,
                const float* __restrict__ ow,
                const float* __restrict__ ob,
                const float* __restrict__ H0,
                const float* __restrict__ C0,
                float* __restrict__ recon,        // [B][L-1][N]
                float* __restrict__ pred)         // [B][N]
{
    const int n = blockIdx.x >> 5;
    const int b = blockIdx.x & 31;
    const int u = threadIdx.x;

    v2f wif[64], wgo[64];
    load_gate_rows(Whh, n, u, wif, wgo);

    const float* Bn = bias + n * 256;
    const v2f bif = {Bn[u],       Bn[u +  64]};
    const v2f bgo = {Bn[u + 128], Bn[u + 192]};
    const float owu = ow[n * DD + u];
    const float obn = ob[n];

    const size_t idx = ((size_t)n * BB + b) * DD + u;
    float h = H0[idx];
    float c = C0[idx];

#pragma unroll 1
    for (int t = 0; t < LL; ++t) {
        v2f aif = bif, ago = bgo;
#pragma unroll
        for (int k = 0; k < 64; ++k) {
            const float hk = bcast(h, k);
            const v2f hh = {hk, hk};
            aif = __builtin_elementwise_fma(wif[k], hh, aif);
            ago = __builtin_elementwise_fma(wgo[k], hh, ago);
        }
        const float gi = sigmoidf_(aif.x), gf = sigmoidf_(aif.y);
        const float gg = tanhf_(ago.x),   go = sigmoidf_(ago.y);
        c = gf * c + gi * gg;
        h = go * tanhf_(c);

        float p = h * owu;
#pragma unroll
        for (int off = 32; off >= 1; off >>= 1) p += __shfl_xor(p, off, 64);
        if (u == 0) {
            const float y = p + obn;
            if (t < LL - 1)
                recon[(size_t)b * ((LL - 1) * NN) + (size_t)t * NN + n] = y;
            else
                pred[(size_t)b * NN + n] = y;
        }
    }
}

extern "C" void kernel_launch(void* const* d_in, const int* in_sizes, int n_in,
                              void* d_out, int out_size, void* d_ws, size_t ws_size,
                              hipStream_t stream) {
    (void)in_sizes; (void)n_in; (void)out_size; (void)ws_size;

    const float* X         = (const float*)d_in[0];
    const float* enc_Wih   = (const float*)d_in[1];
    const float* enc_Whh   = (const float*)d_in[2];
    const float* enc_b     = (const float*)d_in[3];
    const float* pool_w    = (const float*)d_in[4];
    const float* pool_b    = (const float*)d_in[5];
    const float* attn_Wqkv = (const float*)d_in[6];
    const float* attn_bqkv = (const float*)d_in[7];
    const float* attn_Wo   = (const float*)d_in[8];
    const float* attn_bo   = (const float*)d_in[9];
    // d_in[10] = dec_Wih: multiplied by all-zero inputs -> unused
    const float* dec_Whh   = (const float*)d_in[11];
    const float* dec_b     = (const float*)d_in[12];
    const float* init_h_W  = (const float*)d_in[13];
    const float* init_h_b  = (const float*)d_in[14];
    const float* init_c_W  = (const float*)d_in[15];
    const float* init_c_b  = (const float*)d_in[16];
    const float* out_w     = (const float*)d_in[17];
    const float* out_b     = (const float*)d_in[18];

    float* out   = (float*)d_out;
    float* recon = out;                                     // B*(L-1)*N
    float* pred  = out + (size_t)BB * (LL - 1) * NN;        // B*N
    float* cstar = pred + (size_t)BB * NN;                  // B*N*D

    float* Cws = (float*)d_ws;                              // [B][N][D]
    float* Ows = Cws + (size_t)BB * NN * DD;                // [B][N][D]
    // After proj, Cws/Ows are dead -> reuse for H0/C0 ([N][B][D] each)
    float* H0 = Cws;
    float* C0 = Ows;

    enc_kernel<<<dim3(NN * BB), dim3(64), 0, stream>>>(
        X, enc_Wih, enc_Whh, enc_b, pool_w, pool_b, Cws);

    attn_kernel<<<dim3(BB * HH), dim3(256), 0, stream>>>(
        Cws, attn_Wqkv, attn_bqkv, Ows);

    proj_kernel<<<dim3(BB), dim3(256), 0, stream>>>(
        Ows, attn_Wo, attn_bo, cstar);

    dec_init_kernel<<<dim3(NN * BB), dim3(64), 0, stream>>>(
        cstar, init_h_W, init_h_b, init_c_W, init_c_b, H0, C0);

    dec_kernel<<<dim3(NN * BB), dim3(64), 0, stream>>>(
        dec_Whh, dec_b, out_w, out_b, H0, C0, recon, pred);
}